// Round 5
// baseline (1480.717 us; speedup 1.0000x reference)
//
#include <hip/hip_runtime.h>
#include <math.h>

#define BATCH 16
#define SEQ   1024
#define DIM   2048
#define EPS_F 0.1f
#define INV_EPS 10.0f
#define N_ITER 100

typedef short bf16x8 __attribute__((ext_vector_type(8)));
typedef float f32x4  __attribute__((ext_vector_type(4)));

__device__ inline float blo(unsigned int x) { return __uint_as_float(x << 16); }
__device__ inline float bhi(unsigned int x) { return __uint_as_float(x & 0xffff0000u); }

__device__ inline unsigned short f_to_bf16(float f) {
    unsigned int x = __float_as_uint(f);
    unsigned int lsb = (x >> 16) & 1u;
    x += 0x7fffu + lsb;               // round-to-nearest-even
    return (unsigned short)(x >> 16);
}

// async global->LDS, 16B per lane; LDS dest is wave-uniform base + lane*16
__device__ __forceinline__ void gload16(const void* g, void* l) {
    __builtin_amdgcn_global_load_lds(
        (const __attribute__((address_space(1))) void*)g,
        (__attribute__((address_space(3))) void*)l, 16, 0, 0);
}

// ---------------- init: t buffers = 0, flags = 0 ----------------
__global__ void init_state(float* __restrict__ tbuf, unsigned int* __restrict__ flags) {
    int i = blockIdx.x * 256 + threadIdx.x;   // grid 64*256 = 16384
    ((float4*)tbuf)[i] = (float4){0.f, 0.f, 0.f, 0.f};
    if (i < 1024) flags[i] = 0u;
}

// ---------------- normalize + cast to bf16 ----------------
__global__ __launch_bounds__(256) void normalize_kernel(
    const float* __restrict__ student, const float* __restrict__ teacher,
    unsigned short* __restrict__ Sn, unsigned short* __restrict__ Tn)
{
    int rowid  = blockIdx.x;
    int tensor = rowid >> 14;
    int row    = rowid & 16383;
    const float* src = tensor ? teacher : student;
    unsigned short* dst = tensor ? Tn : Sn;
    const float4* p4 = (const float4*)(src + (size_t)row * DIM);
    int t = threadIdx.x;

    float4 a = p4[t];
    float4 b = p4[t + 256];
    float ss = a.x*a.x + a.y*a.y + a.z*a.z + a.w*a.w
             + b.x*b.x + b.y*b.y + b.z*b.z + b.w*b.w;
    #pragma unroll
    for (int m = 32; m; m >>= 1) ss += __shfl_xor(ss, m, 64);
    __shared__ float wss[4];
    if ((t & 63) == 0) wss[t >> 6] = ss;
    __syncthreads();
    float rn = 1.0f / fmaxf(sqrtf(wss[0] + wss[1] + wss[2] + wss[3]), 1e-12f);

    unsigned short o1[4], o2[4];
    o1[0] = f_to_bf16(a.x * rn); o1[1] = f_to_bf16(a.y * rn);
    o1[2] = f_to_bf16(a.z * rn); o1[3] = f_to_bf16(a.w * rn);
    o2[0] = f_to_bf16(b.x * rn); o2[1] = f_to_bf16(b.y * rn);
    o2[2] = f_to_bf16(b.z * rn); o2[3] = f_to_bf16(b.w * rn);
    unsigned short* d = dst + (size_t)row * DIM;
    *(uint2*)(d + 4*t)        = *(uint2*)o1;
    *(uint2*)(d + 1024 + 4*t) = *(uint2*)o2;
}

// ---------------- batched GEMM -> K = exp(-C/eps), bf16 ----------------
// Round-3 structure (global_load_lds width-16, linear [128][32] LDS tiles).
// Measured neutral vs reg-staging -> GEMM is fetch-bound, not issue-bound.
#define TM  128

__global__ __launch_bounds__(256) void gemm_cost_kernel(
    const unsigned short* __restrict__ Tn, const unsigned short* __restrict__ Sn,
    unsigned short* __restrict__ Kmat)
{
    __shared__ __align__(16) unsigned short As[TM * 32];   // 8 KB, linear
    __shared__ __align__(16) unsigned short Bs[TM * 32];   // 8 KB, linear

    int bid  = blockIdx.x;
    int b    = bid >> 6;
    int tile = bid & 63;
    int tm0  = (tile >> 3) * TM;
    int tn0  = (tile & 7)  * TM;

    const unsigned short* Ab = Tn + (size_t)b * SEQ * DIM;
    const unsigned short* Bb = Sn + (size_t)b * SEQ * DIM;

    int t    = threadIdx.x;
    int w    = t >> 6;
    int l    = t & 63;
    int mq   = (w >> 1) * 64;
    int nq   = (w & 1)  * 64;
    int lrow = l & 15;
    int kg   = l >> 4;

    const unsigned short* gA0 = Ab + (size_t)(tm0 + (w << 5) + (l >> 2)) * DIM + ((l & 3) << 3);
    const unsigned short* gA1 = gA0 + (size_t)16 * DIM;
    const unsigned short* gB0 = Bb + (size_t)(tn0 + (w << 5) + (l >> 2)) * DIM + ((l & 3) << 3);
    const unsigned short* gB1 = gB0 + (size_t)16 * DIM;
    unsigned short* lA0 = &As[(w << 10)];
    unsigned short* lA1 = &As[(w << 10) + 512];
    unsigned short* lB0 = &Bs[(w << 10)];
    unsigned short* lB1 = &Bs[(w << 10) + 512];

    f32x4 acc[4][4];
    #pragma unroll
    for (int i = 0; i < 4; i++)
        #pragma unroll
        for (int j = 0; j < 4; j++)
            acc[i][j] = (f32x4){0.f, 0.f, 0.f, 0.f};

    for (int k0 = 0; k0 < DIM; k0 += 32) {
        __syncthreads();
        gload16(gA0 + k0, lA0);
        gload16(gA1 + k0, lA1);
        gload16(gB0 + k0, lB0);
        gload16(gB1 + k0, lB1);
        __syncthreads();

        bf16x8 af[4], bfr[4];
        #pragma unroll
        for (int i = 0; i < 4; i++)
            af[i] = *(const bf16x8*)&As[(mq + i * 16 + lrow) * 32 + kg * 8];
        #pragma unroll
        for (int j = 0; j < 4; j++)
            bfr[j] = *(const bf16x8*)&Bs[(nq + j * 16 + lrow) * 32 + kg * 8];
        #pragma unroll
        for (int i = 0; i < 4; i++)
            #pragma unroll
            for (int j = 0; j < 4; j++)
                acc[i][j] = __builtin_amdgcn_mfma_f32_16x16x32_bf16(af[i], bfr[j], acc[i][j], 0, 0, 0);
    }

    unsigned short* Kb = Kmat + ((size_t)b << 20);
    #pragma unroll
    for (int i = 0; i < 4; i++) {
        #pragma unroll
        for (int j = 0; j < 4; j++) {
            int gcol = tn0 + nq + j * 16 + lrow;
            #pragma unroll
            for (int r = 0; r < 4; r++) {
                int grow = tm0 + mq + i * 16 + kg * 4 + r;
                float cosv = acc[i][j][r];
                float cost = 0.5f - 0.5f * cosv;
                Kb[((size_t)grow << 10) + gcol] = f_to_bf16(__expf(-cost * INV_EPS));
            }
        }
    }
}

// ---------------- persistent Sinkhorn + fused loss ----------------
// Round-5: round-0 structure (256 blocks x 512 thr, 1 block/CU proven
// resident; K on VMEM pipe; plain-write part[]; LLC exchange verbatim),
// ONLY change = per-wave ILP: 8 rows processed as 2 batches of 4 with
//   - 4 independent dwordx4 row loads in flight (vs 1 serial chain)
//   - 4 independent dot chains
//   - 4 butterfly reductions interleaved (serial shfl exposure /4)
// Round-4's TLP approach (512 blocks, 2/CU) risked co-residency deadlock;
// this gets the same latency-hiding with guaranteed-resident geometry.
#define UNPK(A,B,F) do { \
    F[0]=blo(A.x);  F[1]=bhi(A.x);  F[2]=blo(A.y);  F[3]=bhi(A.y);  \
    F[4]=blo(A.z);  F[5]=bhi(A.z);  F[6]=blo(A.w);  F[7]=bhi(A.w);  \
    F[8]=blo(B.x);  F[9]=bhi(B.x);  F[10]=blo(B.y); F[11]=bhi(B.y); \
    F[12]=blo(B.z); F[13]=bhi(B.z); F[14]=blo(B.w); F[15]=bhi(B.w); } while(0)

__global__ __launch_bounds__(512) void sinkhorn_persistent(
    const unsigned short* __restrict__ Kmat,
    float* __restrict__ tbuf,          // [16][4][1024]
    unsigned int* __restrict__ flags,  // [16][64]
    float* __restrict__ partials)      // [256]
{
    __shared__ float part[8 * 1024];   // per-wave column partials
    __shared__ float vsw[1024];        // v, swizzled: v[c] at (c&15)*64 + (c>>4)
    __shared__ float ulds[64];
    __shared__ float wlds[8];

    int idx   = blockIdx.x;
    int b     = (idx & 7) | (((idx >> 3) & 1) << 3);  // idx%8 == b%8 : XCD-pinned
    int slice = idx >> 4;                             // 0..15
    const unsigned short* Kb = Kmat + ((size_t)b << 20);
    float* tb = tbuf + (b << 12);
    unsigned int* flag = flags + b * 64;

    int t    = threadIdx.x;
    int lane = t & 63;
    int w    = t >> 6;                 // wave 0..7
    int r0   = slice << 6;             // this block's 64 rows (also its 64-col zero-slice)

    vsw[t] = 1.0f; vsw[t + 512] = 1.0f;     // v0 = 1 (swizzle of ones is ones)
    __syncthreads();

    unsigned int tgt = 0;
    for (int iter = 0; iter < N_ITER; iter++) {
        // vreg[k] = v[lane*16 + k]  — conflict-free swizzled loads
        float vreg[16];
        #pragma unroll
        for (int k = 0; k < 16; k++) vreg[k] = vsw[k * 64 + lane];

        float tacc[16];
        #pragma unroll
        for (int k = 0; k < 16; k++) tacc[k] = 0.f;

        // ---- fused sweep: 2 batches of 4 rows ----
        #pragma unroll
        for (int bb = 0; bb < 2; bb++) {
            int rowA = r0 + (w << 3) + (bb << 2);
            const uint4* kp0 = (const uint4*)(Kb + ((size_t)(rowA)     << 10) + (lane << 4));
            const uint4* kp1 = (const uint4*)(Kb + ((size_t)(rowA + 1) << 10) + (lane << 4));
            const uint4* kp2 = (const uint4*)(Kb + ((size_t)(rowA + 2) << 10) + (lane << 4));
            const uint4* kp3 = (const uint4*)(Kb + ((size_t)(rowA + 3) << 10) + (lane << 4));
            uint4 a0 = kp0[0], b0 = kp0[1];
            uint4 a1 = kp1[0], b1 = kp1[1];
            uint4 a2 = kp2[0], b2 = kp2[1];
            uint4 a3 = kp3[0], b3 = kp3[1];
            float f0[16], f1[16], f2[16], f3[16];
            UNPK(a0, b0, f0); UNPK(a1, b1, f1);
            UNPK(a2, b2, f2); UNPK(a3, b3, f3);

            float s0 = 0.f, s1 = 0.f, s2 = 0.f, s3 = 0.f;
            #pragma unroll
            for (int k = 0; k < 16; k++) {
                s0 = fmaf(f0[k], vreg[k], s0);
                s1 = fmaf(f1[k], vreg[k], s1);
                s2 = fmaf(f2[k], vreg[k], s2);
                s3 = fmaf(f3[k], vreg[k], s3);
            }
            #pragma unroll
            for (int m = 32; m; m >>= 1) {   // 4 independent chains, pipelined
                s0 += __shfl_xor(s0, m, 64);
                s1 += __shfl_xor(s1, m, 64);
                s2 += __shfl_xor(s2, m, 64);
                s3 += __shfl_xor(s3, m, 64);
            }
            float u0 = (1.0f / 1024.0f) / s0;
            float u1 = (1.0f / 1024.0f) / s1;
            float u2 = (1.0f / 1024.0f) / s2;
            float u3 = (1.0f / 1024.0f) / s3;
            if (lane == 0) {
                int rr = (w << 3) + (bb << 2);
                ulds[rr] = u0; ulds[rr + 1] = u1; ulds[rr + 2] = u2; ulds[rr + 3] = u3;
            }
            #pragma unroll
            for (int k = 0; k < 16; k++) {
                tacc[k] = fmaf(f0[k], u0, tacc[k]);
                tacc[k] = fmaf(f1[k], u1, tacc[k]);
                tacc[k] = fmaf(f2[k], u2, tacc[k]);
                tacc[k] = fmaf(f3[k], u3, tacc[k]);
            }
        }
        // wave partials -> LDS
        #pragma unroll
        for (int k = 0; k < 16; k += 4)
            *(float4*)&part[w * 1024 + lane * 16 + k] =
                (float4){tacc[k], tacc[k+1], tacc[k+2], tacc[k+3]};
        __syncthreads();

        // reduce 8 waves, then LLC atomics (cols 2t, 2t+1)
        float a0 = 0.f, a1 = 0.f;
        #pragma unroll
        for (int g = 0; g < 8; g++) {
            float2 p = *(const float2*)&part[g * 1024 + t * 2];
            a0 += p.x; a1 += p.y;
        }
        int cur = iter & 3;
        float* tcur = tb + (cur << 10);
        atomicAdd(&tcur[t * 2],     a0);
        atomicAdd(&tcur[t * 2 + 1], a1);
        if (t < 64)
            __hip_atomic_store(&tb[(((iter + 2) & 3) << 10) + r0 + t], 0.0f,
                               __ATOMIC_RELAXED, __HIP_MEMORY_SCOPE_AGENT);
        __syncthreads();   // per-wave vmcnt(0): all atomics drained to LLC

        // ---- single LLC barrier per iteration ----
        tgt += 16;
        if (t == 0) {
            __hip_atomic_fetch_add(flag, 1u, __ATOMIC_RELAXED, __HIP_MEMORY_SCOPE_AGENT);
            while (__hip_atomic_load(flag, __ATOMIC_RELAXED, __HIP_MEMORY_SCOPE_AGENT) < tgt)
                __builtin_amdgcn_s_sleep(2);
        }
        __syncthreads();

        // ---- read t (LLC), compute v, store swizzled ----
        float t0 = __hip_atomic_load(&tcur[t * 2],     __ATOMIC_RELAXED, __HIP_MEMORY_SCOPE_AGENT);
        float t1 = __hip_atomic_load(&tcur[t * 2 + 1], __ATOMIC_RELAXED, __HIP_MEMORY_SCOPE_AGENT);
        int c0 = t * 2, c1 = t * 2 + 1;
        vsw[(c0 & 15) * 64 + (c0 >> 4)] = (1.0f / 1024.0f) / t0;
        vsw[(c1 & 15) * 64 + (c1 >> 4)] = (1.0f / 1024.0f) / t1;
        __syncthreads();
    }

    // ---- fused loss over strip: sum_ij u_i K_ij v_j * (-eps ln K_ij) ----
    {
        float vreg[16];
        #pragma unroll
        for (int k = 0; k < 16; k++) vreg[k] = vsw[k * 64 + lane];
        float wsum = 0.f;
        #pragma unroll
        for (int rr = 0; rr < 8; rr++) {
            int row = r0 + w * 8 + rr;
            const unsigned int* kp = (const unsigned int*)(Kb + ((size_t)row << 10) + (lane << 4));
            float s = 0.f;
            #pragma unroll
            for (int q = 0; q < 8; q++) {
                unsigned int kk = kp[q];
                float klo = blo(kk), khi = bhi(kk);
                float clo = -EPS_F * __logf(klo);
                float chi = -EPS_F * __logf(khi);
                s = fmaf(klo * vreg[2 * q],     clo, s);
                s = fmaf(khi * vreg[2 * q + 1], chi, s);
            }
            #pragma unroll
            for (int m = 32; m; m >>= 1) s += __shfl_xor(s, m, 64);
            if (lane == 0) wsum += s * ulds[w * 8 + rr];
        }
        if (lane == 0) wlds[w] = wsum;
    }
    __syncthreads();
    if (t == 0) {
        float s = 0.f;
        #pragma unroll
        for (int g = 0; g < 8; g++) s += wlds[g];
        partials[idx] = s;
    }
}

// ---------------- final reduce ----------------
__global__ __launch_bounds__(256) void loss_final(
    const float* __restrict__ partials, float* __restrict__ out)
{
    int t = threadIdx.x;
    float s = partials[t];
    #pragma unroll
    for (int m = 32; m; m >>= 1) s += __shfl_xor(s, m, 64);
    __shared__ float wp[4];
    if ((t & 63) == 0) wp[t >> 6] = s;
    __syncthreads();
    if (t == 0) out[0] = (wp[0] + wp[1] + wp[2] + wp[3]) * (1.0f / 16.0f);
}

extern "C" void kernel_launch(void* const* d_in, const int* in_sizes, int n_in,
                              void* d_out, int out_size, void* d_ws, size_t ws_size,
                              hipStream_t stream) {
    const float* student = (const float*)d_in[0];
    const float* teacher = (const float*)d_in[1];
    float* out = (float*)d_out;
    char* ws = (char*)d_ws;

    unsigned short* Tn   = (unsigned short*)(ws);                     // 64 MB
    unsigned short* Sn   = (unsigned short*)(ws + 67108864);          // 64 MB
    unsigned short* Kmat = (unsigned short*)(ws + 134217728);         // 32 MB
    float*        tbuf     = (float*)(ws + 167772160);                // 256 KB
    unsigned int* flags    = (unsigned int*)(ws + 167772160 + 262144);// 4 KB
    float*        partials = (float*)(ws + 167772160 + 266240);       // 1 KB

    hipLaunchKernelGGL(init_state, dim3(64), dim3(256), 0, stream, tbuf, flags);
    hipLaunchKernelGGL(normalize_kernel, dim3(32768), dim3(256), 0, stream,
                       student, teacher, Sn, Tn);
    hipLaunchKernelGGL(gemm_cost_kernel, dim3(1024), dim3(256), 0, stream, Tn, Sn, Kmat);
    hipLaunchKernelGGL(sinkhorn_persistent, dim3(256), dim3(512), 0, stream,
                       Kmat, tbuf, flags, partials);
    hipLaunchKernelGGL(loss_final, dim3(1), dim3(256), 0, stream, partials, out);
}